// Round 2
// baseline (805.955 us; speedup 1.0000x reference)
//
#include <hip/hip_runtime.h>
#include <math.h>

// ---------------------------------------------------------------------------
// 3-layer GCN, N=100k nodes, E=3.2M edges.
// Pipeline (all on `stream`, graph-capturable, no float feature atomics):
//   k_detect : decide if edge_index arrived as int32 or int64 (shift flag)
//   k_zero   : zero cnt[] and accum
//   k_count  : in-degree counts (int atomics)
//   k_scan1/2/3 : exclusive prefix sum -> CSR offsets + scatter cursors
//   k_scatter: counting-sort rows by col -> srow[] (CSR of transposed graph)
//   k_prep   : dis = rsqrt(deg), y = x*dis
//   k_layer1 : scalar aggregation s[c]; fused relu(s*W1+b1) @ W2 -> p = g1*dis
//   k_layer2 : wave-per-node 32-dim aggregation + relu + dot(W3) -> q = t*dis
//   k_final  : total = sum_e q[row]*dis[col] + sum_n q[n]*dis[n]
//   k_out    : sigmoid(total + N*b3)
// ---------------------------------------------------------------------------

#define TB 256
#define SCAN_BS 1024

// Edge indexing: if data is int64 (little-endian, values < 2^31), the low
// dword of element i is at dword index 2*i. flag=1 -> shift indices by 1.
__global__ void k_detect(const int* __restrict__ ei, int* __restrict__ flag) {
    __shared__ int any_nonzero;
    if (threadIdx.x == 0) any_nonzero = 0;
    __syncthreads();
    int v = ei[2 * threadIdx.x + 1];   // high dword if int64
    if (v != 0) atomicOr(&any_nonzero, 1);
    __syncthreads();
    if (threadIdx.x == 0) flag[0] = (any_nonzero == 0) ? 1 : 0;
}

__global__ void k_zero(int* __restrict__ cnt, int N, float* __restrict__ accum) {
    int i = blockIdx.x * blockDim.x + threadIdx.x;
    if (i < N) cnt[i] = 0;
    if (i == 0) accum[0] = 0.f;
}

__global__ void k_count(const int* __restrict__ ei, int E,
                        const int* __restrict__ flag, int* __restrict__ cnt) {
    int e = blockIdx.x * blockDim.x + threadIdx.x;
    if (e >= E) return;
    int sh = flag[0];
    int c = ei[(E + e) << sh];
    atomicAdd(&cnt[c], 1);
}

__global__ void k_scan1(const int* __restrict__ cnt, int N,
                        int* __restrict__ off, int* __restrict__ bsum) {
    __shared__ int s[SCAN_BS];
    int t = threadIdx.x;
    int i = blockIdx.x * SCAN_BS + t;
    int v = (i < N) ? cnt[i] : 0;
    s[t] = v;
    __syncthreads();
    for (int d = 1; d < SCAN_BS; d <<= 1) {
        int add = (t >= d) ? s[t - d] : 0;
        __syncthreads();
        s[t] += add;
        __syncthreads();
    }
    int incl = s[t];
    if (i < N) off[i] = incl - v;             // local exclusive
    if (t == SCAN_BS - 1) bsum[blockIdx.x] = incl;
}

__global__ void k_scan2(int* __restrict__ bsum, int nb) {
    if (blockIdx.x == 0 && threadIdx.x == 0) {
        int run = 0;
        for (int b = 0; b < nb; ++b) { int v = bsum[b]; bsum[b] = run; run += v; }
    }
}

__global__ void k_scan3(int* __restrict__ off, int* __restrict__ cur,
                        const int* __restrict__ bsum, int N) {
    int i = blockIdx.x * blockDim.x + threadIdx.x;
    if (i < N) {
        int o = off[i] + bsum[i >> 10];
        off[i] = o;
        cur[i] = o;
    }
}

__global__ void k_scatter(const int* __restrict__ ei, int E,
                          const int* __restrict__ flag,
                          int* __restrict__ cur, int* __restrict__ srow) {
    int e = blockIdx.x * blockDim.x + threadIdx.x;
    if (e >= E) return;
    int sh = flag[0];
    int r = ei[e << sh];
    int c = ei[(E + e) << sh];
    int pos = atomicAdd(&cur[c], 1);
    srow[pos] = r;
}

__global__ void k_prep(const int* __restrict__ cnt, const float* __restrict__ x,
                       float* __restrict__ dis, float* __restrict__ y, int N) {
    int i = blockIdx.x * blockDim.x + threadIdx.x;
    if (i >= N) return;
    float d = rsqrtf((float)(cnt[i] + 1));   // +1 self-loop; deg>0 always
    dis[i] = d;
    y[i] = x[i] * d;
}

// Thread per node: scalar aggregation + fused  p[c][:] = dis[c] * (relu(s*W1+b1) @ W2)
__global__ __launch_bounds__(TB) void k_layer1(
        const int* __restrict__ off, const int* __restrict__ cnt,
        const int* __restrict__ srow, const float* __restrict__ y,
        const float* __restrict__ dis,
        const float* __restrict__ W1, const float* __restrict__ b1,
        const float* __restrict__ W2, float* __restrict__ p, int N) {
    __shared__ float sW1[64], sb1[64];
    __shared__ float4 sW2[512];               // 64x32 as float4 rows
    for (int k = threadIdx.x; k < 64; k += TB) { sW1[k] = W1[k]; sb1[k] = b1[k]; }
    const float4* W2v = (const float4*)W2;
    for (int k = threadIdx.x; k < 512; k += TB) sW2[k] = W2v[k];
    __syncthreads();

    int c = blockIdx.x * blockDim.x + threadIdx.x;
    if (c >= N) return;
    int base = off[c], ne = cnt[c];
    float s_ = 0.f;
    for (int k = 0; k < ne; ++k) s_ += y[srow[base + k]];
    s_ = (s_ + y[c]) * dis[c];

    float4 g[8];
#pragma unroll
    for (int jj = 0; jj < 8; ++jj) g[jj] = make_float4(0.f, 0.f, 0.f, 0.f);
    for (int f = 0; f < 64; ++f) {
        float hf = fmaxf(fmaf(s_, sW1[f], sb1[f]), 0.f);
#pragma unroll
        for (int jj = 0; jj < 8; ++jj) {
            float4 w = sW2[f * 8 + jj];
            g[jj].x = fmaf(hf, w.x, g[jj].x);
            g[jj].y = fmaf(hf, w.y, g[jj].y);
            g[jj].z = fmaf(hf, w.z, g[jj].z);
            g[jj].w = fmaf(hf, w.w, g[jj].w);
        }
    }
    float d = dis[c];
    float4* pv = (float4*)&p[(size_t)c * 32];
#pragma unroll
    for (int jj = 0; jj < 8; ++jj) {
        float4 o;
        o.x = g[jj].x * d; o.y = g[jj].y * d; o.z = g[jj].z * d; o.w = g[jj].w * d;
        pv[jj] = o;
    }
}

// Wave per node: 32-dim aggregation (half-wave per edge), relu, dot W3 -> q
__global__ __launch_bounds__(TB) void k_layer2(
        const int* __restrict__ off, const int* __restrict__ cnt,
        const int* __restrict__ srow, const float* __restrict__ p,
        const float* __restrict__ dis, const float* __restrict__ b2,
        const float* __restrict__ W3, float* __restrict__ q, int N) {
    int gtid = blockIdx.x * blockDim.x + threadIdx.x;
    int c = gtid >> 6;                         // wave id = node
    if (c >= N) return;
    int lane = threadIdx.x & 63;
    int j = lane & 31;
    int h = lane >> 5;

    int base = off[c], ne = cnt[c];
    float acc = 0.f;
    for (int k = h; k < ne; k += 2) {
        int r = srow[base + k];                // broadcast within half-wave
        acc += p[(size_t)r * 32 + j];          // 128 B coalesced per half-wave
    }
    acc += __shfl_down(acc, 32);               // combine the two halves

    float val = dis[c] * (acc + p[(size_t)c * 32 + j]) + b2[j];
    float h2 = fmaxf(val, 0.f);
    float prod = h2 * W3[j];
    prod += __shfl_down(prod, 16);
    prod += __shfl_down(prod, 8);
    prod += __shfl_down(prod, 4);
    prod += __shfl_down(prod, 2);
    prod += __shfl_down(prod, 1);
    if (lane == 0) q[c] = prod * dis[c];
}

__global__ __launch_bounds__(TB) void k_final(
        const int* __restrict__ ei, int E, const int* __restrict__ flag,
        const float* __restrict__ q, const float* __restrict__ dis, int N,
        float* __restrict__ accum) {
    __shared__ float red[TB];
    int i = blockIdx.x * blockDim.x + threadIdx.x;
    float v = 0.f;
    if (i < E) {
        int sh = flag[0];
        int r = ei[i << sh];
        int c = ei[(E + i) << sh];
        v = q[r] * dis[c];
    } else if (i < E + N) {
        int n2 = i - E;
        v = q[n2] * dis[n2];                   // self-loop term
    }
    red[threadIdx.x] = v;
    __syncthreads();
    for (int d = TB / 2; d > 0; d >>= 1) {
        if (threadIdx.x < d) red[threadIdx.x] += red[threadIdx.x + d];
        __syncthreads();
    }
    if (threadIdx.x == 0) atomicAdd(accum, red[0]);
}

__global__ void k_out(const float* __restrict__ accum, const float* __restrict__ b3,
                      float* __restrict__ out, float Nf) {
    float z = accum[0] + Nf * b3[0];
    out[0] = 1.f / (1.f + expf(-z));
}

extern "C" void kernel_launch(void* const* d_in, const int* in_sizes, int n_in,
                              void* d_out, int out_size, void* d_ws, size_t ws_size,
                              hipStream_t stream) {
    const float* x  = (const float*)d_in[0];
    const int*   ei = (const int*)d_in[1];
    const float* W1 = (const float*)d_in[2];
    const float* b1 = (const float*)d_in[3];
    const float* W2 = (const float*)d_in[4];
    const float* b2 = (const float*)d_in[5];
    const float* W3 = (const float*)d_in[6];
    const float* b3 = (const float*)d_in[7];
    float* out = (float*)d_out;

    const int N = in_sizes[0];        // 100000
    const int E = in_sizes[1] / 2;    // 3200000

    // Workspace carve-up (256 B aligned)
    char* w = (char*)d_ws;
    size_t o = 0;
    auto alloc = [&](size_t bytes) -> void* {
        void* ptr = w + o;
        o += (bytes + 255) & ~(size_t)255;
        return ptr;
    };
    int*   cnt   = (int*)  alloc((size_t)N * 4);
    float* accum = (float*)alloc(256);
    int*   flag  = (int*)  alloc(256);
    int*   off   = (int*)  alloc((size_t)N * 4);
    int*   cur   = (int*)  alloc((size_t)N * 4);
    int*   bsum  = (int*)  alloc(4096);
    float* dis   = (float*)alloc((size_t)N * 4);
    float* y     = (float*)alloc((size_t)N * 4);
    float* q     = (float*)alloc((size_t)N * 4);
    int*   srow  = (int*)  alloc((size_t)E * 4);
    float* p     = (float*)alloc((size_t)N * 32 * 4);
    if (o > ws_size) return;  // workspace too small: fail loudly (output stays poisoned)

    const int nbE = (E + TB - 1) / TB;
    const int nbN = (N + TB - 1) / TB;
    const int nbScan = (N + SCAN_BS - 1) / SCAN_BS;

    k_detect<<<1, 128, 0, stream>>>(ei, flag);
    k_zero<<<nbN, TB, 0, stream>>>(cnt, N, accum);
    k_count<<<nbE, TB, 0, stream>>>(ei, E, flag, cnt);
    k_scan1<<<nbScan, SCAN_BS, 0, stream>>>(cnt, N, off, bsum);
    k_scan2<<<1, 1, 0, stream>>>(bsum, nbScan);
    k_scan3<<<nbN, TB, 0, stream>>>(off, cur, bsum, N);
    k_scatter<<<nbE, TB, 0, stream>>>(ei, E, flag, cur, srow);
    k_prep<<<nbN, TB, 0, stream>>>(cnt, x, dis, y, N);
    k_layer1<<<nbN, TB, 0, stream>>>(off, cnt, srow, y, dis, W1, b1, W2, p, N);
    k_layer2<<<(N + 3) / 4, TB, 0, stream>>>(off, cnt, srow, p, dis, b2, W3, q, N);
    k_final<<<(E + N + TB - 1) / TB, TB, 0, stream>>>(ei, E, flag, q, dis, N, accum);
    k_out<<<1, 1, 0, stream>>>(accum, b3, out, (float)N);
}